// Round 2
// baseline (163.751 us; speedup 1.0000x reference)
//
#include <hip/hip_runtime.h>

// QuadraticConv2D: B=8 H=56 W=56 C=64 O=128, 55 quadratic pairs over (ones + 9 shifts)
// GEMM M=25088 pixels, K=55x64, N=128; A generated on the fly from 3 staged rows.
// R2: bf16 row staging, ping-pong Q (1 barrier/pair), 512 threads (8 waves: 2 Mh x 4 Nq).

#define CB 8
#define CH 56
#define CW 56
#define CC 64
#define CO 128
#define NPAIR 55
#define RS 72   // row stride in shorts: 144B, 16B-aligned, conflict-free per 8-lane group
#define QS 72   // Q stride in shorts

typedef __attribute__((ext_vector_type(8))) short bf8_t;   // 8 x bf16 (4 VGPRs)
typedef __attribute__((ext_vector_type(4))) float f4_t;    // MFMA accumulator frag

__device__ __forceinline__ unsigned short pack_bf16(float f) {
  unsigned u = __float_as_uint(f);
  return (unsigned short)((u + 0x8000u) >> 16);
}
__device__ __forceinline__ float bf16_to_f32(unsigned short h) {
  return __uint_as_float(((unsigned)h) << 16);
}

// ---- prep: kernel [55][64][128] f32 -> Bt [55][128][64] bf16 (n-major, k contiguous)
__global__ __launch_bounds__(256) void prep_kernel(const float* __restrict__ K,
                                                   unsigned short* __restrict__ Bt) {
  __shared__ float tile[CC * CO];
  const int p = blockIdx.x;
  const int t = threadIdx.x;
  const float* src = K + (size_t)p * CC * CO;
#pragma unroll
  for (int e = 0; e < 8; ++e) {
    const int idx = t * 4 + e * 1024;
    *(float4*)&tile[idx] = *(const float4*)&src[idx];
  }
  __syncthreads();
  const int n = t & 127;
  const int kh = t >> 7;  // k-half: 0 or 1
  unsigned short ov[32];
#pragma unroll
  for (int k = 0; k < 32; ++k)
    ov[k] = pack_bf16(tile[(kh * 32 + k) * CO + n]);
  unsigned short* dst = Bt + ((size_t)p * CO + n) * CC + kh * 32;
#pragma unroll
  for (int g = 0; g < 4; ++g)
    *(bf8_t*)(dst + g * 8) = *(const bf8_t*)&ov[g * 8];
}

// ---- main: one block per (b,h) row. 512 threads = 8 waves: wave = (mh, nq).
// Wave covers M-half mh*32..+32 (of 64, 56 real) and N-quarter nq*32..+32.
__global__ __launch_bounds__(512, 4) void quad_kernel(const float* __restrict__ in,
                                                      const unsigned short* __restrict__ Bt,
                                                      float* __restrict__ out) {
  __shared__ unsigned short rowsB[3][64][RS];  // 3 input rows (bf16), col = w+1, 27.6 KB
  __shared__ unsigned short Q[2][64][QS];      // ping-pong quad tile, 18.4 KB

  const int t = threadIdx.x;
  const int b = blockIdx.x / CH;
  const int h = blockIdx.x % CH;

  // stage 3 input rows into LDS (bf16) with zero halo (w=-1, w>=56) / zero OOB rows
  {
    const int col = t >> 3;          // 0..63
    const int cg = (t & 7) * 8;      // channel group of 8
    const int w = col - 1;
#pragma unroll
    for (int r = 0; r < 3; ++r) {
      const int hh = h + r - 1;
      const bool valid = (hh >= 0) && (hh < CH) && (w >= 0) && (w < CW);
      float4 v0 = make_float4(0.f, 0.f, 0.f, 0.f), v1 = v0;
      if (valid) {
        const float* s = in + (((size_t)(b * CH + hh)) * CW + w) * CC + cg;
        v0 = *(const float4*)(s);
        v1 = *(const float4*)(s + 4);
      }
      unsigned short pv[8];
      pv[0] = pack_bf16(v0.x); pv[1] = pack_bf16(v0.y);
      pv[2] = pack_bf16(v0.z); pv[3] = pack_bf16(v0.w);
      pv[4] = pack_bf16(v1.x); pv[5] = pack_bf16(v1.y);
      pv[6] = pack_bf16(v1.z); pv[7] = pack_bf16(v1.w);
      *(bf8_t*)&rowsB[r][col][cg] = *(const bf8_t*)pv;
    }
  }

  const int lane = t & 63;
  const int wid = t >> 6;
  const int mh = wid >> 2;   // 0..1: M-half
  const int nq = wid & 3;    // 0..3: N-quarter
  const int nl = lane & 15;
  const int qd = lane >> 4;

  f4_t acc[2][2];
#pragma unroll
  for (int mt = 0; mt < 2; ++mt)
#pragma unroll
    for (int nt = 0; nt < 2; ++nt)
      acc[mt][nt] = (f4_t){0.f, 0.f, 0.f, 0.f};

  // B-frag base: Bt[p][n][k], n = nq*32 + nt*16 + nl, k = ks*32 + qd*8
  const unsigned short* Bl = Bt + ((size_t)(nq * 32 + nl)) * CC + qd * 8;
  bf8_t bcur[2][2], bnext[2][2];
#pragma unroll
  for (int nt = 0; nt < 2; ++nt)
#pragma unroll
    for (int ks = 0; ks < 2; ++ks)
      bcur[nt][ks] = *(const bf8_t*)(Bl + nt * 16 * CC + ks * 32);

  const int gm = t >> 3;         // gen: pixel m (0..63)
  const int gc = (t & 7) * 8;    // gen: channel group of 8

  const bf8_t ones8 = {0x3F80, 0x3F80, 0x3F80, 0x3F80, 0x3F80, 0x3F80, 0x3F80, 0x3F80};

  __syncthreads();  // rowsB ready

  int pi = 0, pj = 0;
#pragma unroll 1
  for (int p = 0; p < NPAIR; ++p) {
    // ---- generate Q[p&1][m][c] = S_pi[m][c] * S_pj[m][c] (bf16 x bf16 -> bf16)
    {
      bf8_t ua, ub;
      if (pi > 0) {
        const int s = pi - 1, rr = s / 3, sc = s % 3;
        int ca = gm + sc; ca = ca > 63 ? 63 : ca;
        ua = *(const bf8_t*)&rowsB[rr][ca][gc];
      } else ua = ones8;
      if (pj > 0) {
        const int s = pj - 1, rr = s / 3, sc = s % 3;
        int cb = gm + sc; cb = cb > 63 ? 63 : cb;
        ub = *(const bf8_t*)&rowsB[rr][cb][gc];
      } else ub = ones8;
      unsigned short qv[8];
#pragma unroll
      for (int e = 0; e < 8; ++e)
        qv[e] = pack_bf16(bf16_to_f32((unsigned short)ua[e]) *
                          bf16_to_f32((unsigned short)ub[e]));
      *(bf8_t*)&Q[p & 1][gm][gc] = *(const bf8_t*)qv;
    }
    // prefetch next pair's B-frags (L2-resident)
    if (p < NPAIR - 1) {
      const unsigned short* bp = Bl + (size_t)(p + 1) * CO * CC;
#pragma unroll
      for (int nt = 0; nt < 2; ++nt)
#pragma unroll
        for (int ks = 0; ks < 2; ++ks)
          bnext[nt][ks] = *(const bf8_t*)(bp + nt * 16 * CC + ks * 32);
    }
    __syncthreads();  // Q[p&1] written; also licenses overwrite of Q[(p+1)&1]
    // ---- MFMA: K=64 (2 ksteps of 32)
#pragma unroll
    for (int ks = 0; ks < 2; ++ks) {
      bf8_t a[2];
#pragma unroll
      for (int mt = 0; mt < 2; ++mt)
        a[mt] = *(const bf8_t*)&Q[p & 1][mh * 32 + mt * 16 + nl][ks * 32 + qd * 8];
#pragma unroll
      for (int mt = 0; mt < 2; ++mt)
#pragma unroll
        for (int nt = 0; nt < 2; ++nt)
          acc[mt][nt] = __builtin_amdgcn_mfma_f32_16x16x32_bf16(a[mt], bcur[nt][ks], acc[mt][nt], 0, 0, 0);
    }
    if (p < NPAIR - 1) {
#pragma unroll
      for (int nt = 0; nt < 2; ++nt)
#pragma unroll
        for (int ks = 0; ks < 2; ++ks)
          bcur[nt][ks] = bnext[nt][ks];
    }
    ++pj;
    if (pj == 10) { ++pi; pj = pi; }
  }

  // ---- epilogue: C/D layout col=lane&15 (n), row=(lane>>4)*4+reg (m)
  float* obase = out + ((size_t)(b * CH + h) * CW) * CO + nq * 32;
#pragma unroll
  for (int mt = 0; mt < 2; ++mt)
#pragma unroll
    for (int r4 = 0; r4 < 4; ++r4) {
      const int wp = mh * 32 + mt * 16 + qd * 4 + r4;
      if (wp < CW) {
#pragma unroll
        for (int nt = 0; nt < 2; ++nt)
          obase[(size_t)wp * CO + nt * 16 + nl] = acc[mt][nt][r4];
      }
    }
}

extern "C" void kernel_launch(void* const* d_in, const int* in_sizes, int n_in,
                              void* d_out, int out_size, void* d_ws, size_t ws_size,
                              hipStream_t stream) {
  const float* in = (const float*)d_in[0];      // [8,56,56,64] f32
  const float* K = (const float*)d_in[1];       // [55,64,128] f32
  float* out = (float*)d_out;                   // [8,56,56,128] f32
  unsigned short* Bt = (unsigned short*)d_ws;   // [55][128][64] bf16 = 901,120 B
  (void)in_sizes; (void)n_in; (void)out_size; (void)ws_size;

  prep_kernel<<<NPAIR, 256, 0, stream>>>(K, Bt);
  quad_kernel<<<CB * CH, 512, 0, stream>>>(in, Bt, out);
}

// Round 3
// 115.983 us; speedup vs baseline: 1.4118x; 1.4118x over previous
//
#include <hip/hip_runtime.h>

// QuadraticConv2D: B=8 H=56 W=56 C=64 O=128, 55 quadratic pairs over (ones + 9 shifts)
// GEMM M=25088 pixels, K=55x64, N=128; A generated on the fly from 3 staged rows.
// R3: 256 thr / 4 waves (no B-frag duplication), bf16 rows, software-pipelined
//     gen(p+1) || MFMA(p) with distinct Q0/Q1 buffers, 1 barrier per pair.

#define CB 8
#define CH 56
#define CW 56
#define CC 64
#define CO 128
#define NPAIR 55
#define RS 72   // row stride in shorts (144 B): quarter-wave b128 phases conflict-free
#define QS 72   // Q stride in shorts

typedef __attribute__((ext_vector_type(8))) short bf8_t;   // 8 x bf16 (4 VGPRs)
typedef __attribute__((ext_vector_type(4))) float f4_t;    // MFMA accumulator frag

static __device__ __forceinline__ unsigned short pack_bf16(float f) {
  unsigned u = __float_as_uint(f);
  return (unsigned short)((u + 0x8000u) >> 16);
}
static __device__ __forceinline__ float bf16_to_f32(unsigned short h) {
  return __uint_as_float(((unsigned)h) << 16);
}

// ---- prep: kernel [55][64][128] f32 -> Bt [55][128][64] bf16 (n-major, k contiguous)
__global__ __launch_bounds__(256) void prep_kernel(const float* __restrict__ K,
                                                   unsigned short* __restrict__ Bt) {
  __shared__ float tile[CC * CO];
  const int p = blockIdx.x;
  const int t = threadIdx.x;
  const float* src = K + (size_t)p * CC * CO;
#pragma unroll
  for (int e = 0; e < 8; ++e) {
    const int idx = t * 4 + e * 1024;
    *(float4*)&tile[idx] = *(const float4*)&src[idx];
  }
  __syncthreads();
  const int n = t & 127;
  const int kh = t >> 7;
  unsigned short ov[32];
#pragma unroll
  for (int k = 0; k < 32; ++k)
    ov[k] = pack_bf16(tile[(kh * 32 + k) * CO + n]);
  unsigned short* dst = Bt + ((size_t)p * CO + n) * CC + kh * 32;
#pragma unroll
  for (int g = 0; g < 4; ++g)
    *(bf8_t*)(dst + g * 8) = *(const bf8_t*)&ov[g * 8];
}

// ---- main: one block per (b,h) row. 256 threads = 4 waves, wave = N-quarter (no B dup).
__global__ __launch_bounds__(256, 2) void quad_kernel(const float* __restrict__ in,
                                                      const unsigned short* __restrict__ Bt,
                                                      float* __restrict__ out) {
  __shared__ unsigned short rowsB[3][64][RS];  // 3 input rows (bf16), col = w+1, 27.6 KB
  __shared__ unsigned short Q0[64][QS];        // quad tile buffers (9.2 KB each)
  __shared__ unsigned short Q1[64][QS];

  const int t = threadIdx.x;
  const int b = blockIdx.x / CH;
  const int h = blockIdx.x % CH;

  const int gm = t >> 2;          // gen/stage: pixel m (0..63)
  const int gc = (t & 3) * 16;    // gen/stage: channel group of 16

  // stage 3 input rows into LDS (bf16) with zero halo
  {
    const int w = gm - 1;
#pragma unroll
    for (int r = 0; r < 3; ++r) {
      const int hh = h + r - 1;
      const bool valid = (hh >= 0) && (hh < CH) && (w >= 0) && (w < CW);
      float4 v0 = make_float4(0.f, 0.f, 0.f, 0.f), v1 = v0, v2 = v0, v3 = v0;
      if (valid) {
        const float* s = in + (((size_t)(b * CH + hh)) * CW + w) * CC + gc;
        v0 = *(const float4*)(s);
        v1 = *(const float4*)(s + 4);
        v2 = *(const float4*)(s + 8);
        v3 = *(const float4*)(s + 12);
      }
      unsigned short pv[16];
      pv[0] = pack_bf16(v0.x); pv[1] = pack_bf16(v0.y); pv[2] = pack_bf16(v0.z); pv[3] = pack_bf16(v0.w);
      pv[4] = pack_bf16(v1.x); pv[5] = pack_bf16(v1.y); pv[6] = pack_bf16(v1.z); pv[7] = pack_bf16(v1.w);
      pv[8] = pack_bf16(v2.x); pv[9] = pack_bf16(v2.y); pv[10] = pack_bf16(v2.z); pv[11] = pack_bf16(v2.w);
      pv[12] = pack_bf16(v3.x); pv[13] = pack_bf16(v3.y); pv[14] = pack_bf16(v3.z); pv[15] = pack_bf16(v3.w);
      unsigned short* d = &rowsB[r][gm][gc];
      *(bf8_t*)(d) = *(const bf8_t*)&pv[0];
      *(bf8_t*)(d + 8) = *(const bf8_t*)&pv[8];
    }
  }

  const int lane = t & 63;
  const int wid = t >> 6;     // N-quarter 0..3
  const int nl = lane & 15;
  const int qd = lane >> 4;

  f4_t acc[4][2];
#pragma unroll
  for (int mt = 0; mt < 4; ++mt)
#pragma unroll
    for (int nt = 0; nt < 2; ++nt)
      acc[mt][nt] = (f4_t){0.f, 0.f, 0.f, 0.f};

  // B-frag base: Bt[p][n][k], n = wid*32 + nt*16 + nl, k = ks*32 + qd*8
  const unsigned short* Bl = Bt + ((size_t)(wid * 32 + nl)) * CC + qd * 8;
  bf8_t bcur[2][2], bnext[2][2];
#pragma unroll
  for (int nt = 0; nt < 2; ++nt)
#pragma unroll
    for (int ks = 0; ks < 2; ++ks)
      bcur[nt][ks] = *(const bf8_t*)(Bl + nt * 16 * CC + ks * 32);

  // prologue: Q0 = pair (0,0) = ones
  {
    unsigned short* d = &Q0[gm][gc];
    const bf8_t one8 = {0x3F80, 0x3F80, 0x3F80, 0x3F80, 0x3F80, 0x3F80, 0x3F80, 0x3F80};
    *(bf8_t*)(d) = one8;
    *(bf8_t*)(d + 8) = one8;
  }
  __syncthreads();

  int gpi = 0, gpj = 0;  // current pair; advanced to p+1 inside each step

  // One step: MFMA(pair p from QR) overlapped with gen(pair p+1 into QW), 1 barrier.
#define STEP(QR, QW, PAIRP)                                                          \
  {                                                                                  \
    ++gpj; if (gpj == 10) { ++gpi; gpj = gpi; }                                      \
    const bool doprod = (gpi > 0);                                                   \
    bf8_t ua0 = {}, ua1 = {}, ub0, ub1;                                              \
    {                                                                                \
      const int sb = gpj - 1;                                                        \
      int cb = gm + sb % 3; cb = cb > 63 ? 63 : cb;                                  \
      const unsigned short* pb = &rowsB[sb / 3][cb][gc];                             \
      ub0 = *(const bf8_t*)pb; ub1 = *(const bf8_t*)(pb + 8);                        \
      if (doprod) {                                                                  \
        const int sa = gpi - 1;                                                      \
        int ca = gm + sa % 3; ca = ca > 63 ? 63 : ca;                                \
        const unsigned short* pa = &rowsB[sa / 3][ca][gc];                           \
        ua0 = *(const bf8_t*)pa; ua1 = *(const bf8_t*)(pa + 8);                      \
      }                                                                              \
    }                                                                                \
    /* prefetch B-frags for pair p+1 (L2-resident; consumed after barrier) */        \
    {                                                                                \
      const unsigned short* bp = Bl + (size_t)((PAIRP) + 1) * CO * CC;               \
      _Pragma("unroll") for (int nt = 0; nt < 2; ++nt)                               \
        _Pragma("unroll") for (int ks = 0; ks < 2; ++ks)                             \
          bnext[nt][ks] = *(const bf8_t*)(bp + nt * 16 * CC + ks * 32);              \
    }                                                                                \
    /* MFMA pair p from QR */                                                        \
    _Pragma("unroll") for (int ks = 0; ks < 2; ++ks) {                               \
      bf8_t a[4];                                                                    \
      _Pragma("unroll") for (int mt = 0; mt < 4; ++mt)                               \
        a[mt] = *(const bf8_t*)&QR[mt * 16 + nl][ks * 32 + qd * 8];                  \
      _Pragma("unroll") for (int mt = 0; mt < 4; ++mt)                               \
        _Pragma("unroll") for (int nt = 0; nt < 2; ++nt)                             \
          acc[mt][nt] = __builtin_amdgcn_mfma_f32_16x16x32_bf16(a[mt], bcur[nt][ks], \
                                                                acc[mt][nt], 0, 0, 0); \
    }                                                                                \
    /* gen products -> QW (pair p+1) */                                              \
    {                                                                                \
      unsigned short qv[16];                                                         \
      if (doprod) {                                                                  \
        _Pragma("unroll") for (int e = 0; e < 8; ++e) {                              \
          qv[e] = pack_bf16(bf16_to_f32((unsigned short)ua0[e]) *                    \
                            bf16_to_f32((unsigned short)ub0[e]));                    \
          qv[8 + e] = pack_bf16(bf16_to_f32((unsigned short)ua1[e]) *                \
                                bf16_to_f32((unsigned short)ub1[e]));                \
        }                                                                            \
      } else {                                                                       \
        _Pragma("unroll") for (int e = 0; e < 8; ++e) {                              \
          qv[e] = (unsigned short)ub0[e];                                            \
          qv[8 + e] = (unsigned short)ub1[e];                                        \
        }                                                                            \
      }                                                                              \
      unsigned short* d = &QW[gm][gc];                                               \
      *(bf8_t*)(d) = *(const bf8_t*)&qv[0];                                          \
      *(bf8_t*)(d + 8) = *(const bf8_t*)&qv[8];                                      \
    }                                                                                \
    __syncthreads();                                                                 \
    _Pragma("unroll") for (int nt = 0; nt < 2; ++nt)                                 \
      _Pragma("unroll") for (int ks = 0; ks < 2; ++ks)                               \
        bcur[nt][ks] = bnext[nt][ks];                                                \
  }

#pragma unroll 1
  for (int p = 0; p < NPAIR - 1; p += 2) {
    STEP(Q0, Q1, p);
    STEP(Q1, Q0, p + 1);
  }
  // final pair 54 (even) from Q0; no gen, no prefetch
#pragma unroll
  for (int ks = 0; ks < 2; ++ks) {
    bf8_t a[4];
#pragma unroll
    for (int mt = 0; mt < 4; ++mt)
      a[mt] = *(const bf8_t*)&Q0[mt * 16 + nl][ks * 32 + qd * 8];
#pragma unroll
    for (int mt = 0; mt < 4; ++mt)
#pragma unroll
      for (int nt = 0; nt < 2; ++nt)
        acc[mt][nt] = __builtin_amdgcn_mfma_f32_16x16x32_bf16(a[mt], bcur[nt][ks], acc[mt][nt], 0, 0, 0);
  }
#undef STEP

  // epilogue: C/D layout col=lane&15 (n), row=(lane>>4)*4+reg (m)
  float* obase = out + ((size_t)(b * CH + h) * CW) * CO + wid * 32;
#pragma unroll
  for (int mt = 0; mt < 4; ++mt)
#pragma unroll
    for (int r4 = 0; r4 < 4; ++r4) {
      const int wp = mt * 16 + qd * 4 + r4;
      if (wp < CW) {
#pragma unroll
        for (int nt = 0; nt < 2; ++nt)
          obase[(size_t)wp * CO + nt * 16 + nl] = acc[mt][nt][r4];
      }
    }
}

extern "C" void kernel_launch(void* const* d_in, const int* in_sizes, int n_in,
                              void* d_out, int out_size, void* d_ws, size_t ws_size,
                              hipStream_t stream) {
  const float* in = (const float*)d_in[0];      // [8,56,56,64] f32
  const float* K = (const float*)d_in[1];       // [55,64,128] f32
  float* out = (float*)d_out;                   // [8,56,56,128] f32
  unsigned short* Bt = (unsigned short*)d_ws;   // [55][128][64] bf16 = 901,120 B
  (void)in_sizes; (void)n_in; (void)out_size; (void)ws_size;

  prep_kernel<<<NPAIR, 256, 0, stream>>>(K, Bt);
  quad_kernel<<<CB * CH, 256, 0, stream>>>(in, Bt, out);
}